// Round 3
// baseline (819.944 us; speedup 1.0000x reference)
//
#include <hip/hip_runtime.h>
#include <math.h>

#define N_TOK  16384
#define DIM    4096
#define NE     64
#define CAP    640
#define TOK_PER_BLOCK 128
#define TOK_PER_WAVE  32
#define NTILES (N_TOK / TOK_PER_BLOCK)  // 128
#define KSTAGE 64   // k per LDS W-stage
#define KCH    16   // k per register chunk

typedef float vfloat16 __attribute__((ext_vector_type(16)));

// ws layout:
// [0,256):               counts (64 int, zeroed per call)
// [256, 256+128K):       ws_idx   (int,   N*2)
// [256+128K, 256+256K):  ws_probs (float, N*2)
// [262400, ...):         partials (KS * 64 * N floats, layout [split][expert][token])

// GEMM: lane <-> expert. W staged via LDS (coalesced, per-lane ds_read_b128).
// x is WAVE-UNIFORM -> s_load_dwordx16 of contiguous 64B row segments (SGPRs),
// used as the scalar operand of v_fmac. x read exactly once, no LDS, no VGPRs.
template<int KS>
__global__ __launch_bounds__(256, 4) void gemm_logits_kernel(
    const float* __restrict__ x, const float* __restrict__ W,
    float* __restrict__ partials) {
  const int tile  = blockIdx.x & (NTILES - 1);
  const int split = blockIdx.x / NTILES;
  const int klen  = DIM / KS;
  const int k0    = split * klen;

  __shared__ float wlds[(KSTAGE / 4) * NE * 4];  // [k4][e][4], 16 KB

  const int tid  = threadIdx.x;
  const int lane = tid & 63;                  // expert id
  const int wave = tid >> 6;
  // wave-uniform token base (forced into SGPR)
  const int t0 = __builtin_amdgcn_readfirstlane(tile * TOK_PER_BLOCK + wave * TOK_PER_WAVE);

  float acc[TOK_PER_WAVE];
#pragma unroll
  for (int i = 0; i < TOK_PER_WAVE; ++i) acc[i] = 0.f;

  const int se  = tid >> 2;  // staging: expert 0..63
  const int skq = tid & 3;   // staging: k quarter

  for (int ks0 = 0; ks0 < klen; ks0 += KSTAGE) {
    // stage W strip: 64 experts x 64 k -> LDS [k4][e][4]
#pragma unroll
    for (int i = 0; i < 4; ++i) {
      const int kk = skq * 16 + i * 4;  // 0..63
      const float4 v = *(const float4*)(W + (size_t)se * DIM + k0 + ks0 + kk);
      *(float4*)&wlds[(kk >> 2) * (NE * 4) + se * 4] = v;
    }
    __syncthreads();

#pragma unroll
    for (int c = 0; c < KSTAGE / KCH; ++c) {  // 4 chunks of 16 k
      // per-lane W fragment for this 16-k chunk
      float w[KCH];
#pragma unroll
      for (int q = 0; q < 4; ++q) {
        const float4 v = *(const float4*)&wlds[(c * 4 + q) * (NE * 4) + lane * 4];
        w[q * 4 + 0] = v.x; w[q * 4 + 1] = v.y;
        w[q * 4 + 2] = v.z; w[q * 4 + 3] = v.w;
      }
      const int kbase = k0 + ks0 + c * KCH;  // uniform
#pragma unroll
      for (int tg = 0; tg < TOK_PER_WAVE / 4; ++tg) {
        // 4 tokens: wave-uniform contiguous 64B scalar loads
        vfloat16 xs0 = *(const vfloat16*)(x + (size_t)(t0 + tg * 4 + 0) * DIM + kbase);
        vfloat16 xs1 = *(const vfloat16*)(x + (size_t)(t0 + tg * 4 + 1) * DIM + kbase);
        vfloat16 xs2 = *(const vfloat16*)(x + (size_t)(t0 + tg * 4 + 2) * DIM + kbase);
        vfloat16 xs3 = *(const vfloat16*)(x + (size_t)(t0 + tg * 4 + 3) * DIM + kbase);
#pragma unroll
        for (int kk = 0; kk < KCH; ++kk) {
          acc[tg * 4 + 0] = fmaf(xs0[kk], w[kk], acc[tg * 4 + 0]);
          acc[tg * 4 + 1] = fmaf(xs1[kk], w[kk], acc[tg * 4 + 1]);
          acc[tg * 4 + 2] = fmaf(xs2[kk], w[kk], acc[tg * 4 + 2]);
          acc[tg * 4 + 3] = fmaf(xs3[kk], w[kk], acc[tg * 4 + 3]);
        }
      }
    }
    __syncthreads();
  }

  // partials[split][expert=lane][t0..t0+31] — makes route reads coalesced
  float* outp = partials + (size_t)split * NE * N_TOK + (size_t)lane * N_TOK + t0;
#pragma unroll
  for (int i = 0; i < TOK_PER_WAVE / 4; ++i)
    *(float4*)(outp + i * 4) =
        make_float4(acc[i * 4], acc[i * 4 + 1], acc[i * 4 + 2], acc[i * 4 + 3]);
}

template<int KS>
__global__ __launch_bounds__(64) void route_kernel(
    const float* __restrict__ partials,
    float* __restrict__ out, int* __restrict__ ws_idx,
    float* __restrict__ ws_probs, int* __restrict__ counts) {
  __shared__ int cnt[NE];
  const int tid = threadIdx.x;
  cnt[tid] = 0;
  __syncthreads();
  const int t = blockIdx.x * 64 + tid;

  // top-2 with jax.lax.top_k tie semantics (strict > keeps lower index)
  float b1 = -INFINITY, b2 = -INFINITY;
  int i1 = 0, i2 = 0;
#pragma unroll
  for (int e = 0; e < NE; ++e) {
    float s = partials[(size_t)e * N_TOK + t];  // coalesced across lanes
#pragma unroll
    for (int sp = 1; sp < KS; ++sp)
      s += partials[(size_t)sp * NE * N_TOK + (size_t)e * N_TOK + t];
    if (s > b1)      { b2 = b1; i2 = i1; b1 = s; i1 = e; }
    else if (s > b2) { b2 = s; i2 = e; }
  }
  const float ed = expf(b2 - b1);
  const float p1 = 1.0f / (1.0f + ed);
  const float p2 = ed / (1.0f + ed);

  out[(size_t)t * 2]     = p1;
  out[(size_t)t * 2 + 1] = p2;
  out[(size_t)N_TOK * 2 + t * 2]     = (float)i1;  // indices stored as f32
  out[(size_t)N_TOK * 2 + t * 2 + 1] = (float)i2;
  ws_idx[t * 2] = i1;  ws_idx[t * 2 + 1] = i2;
  ws_probs[t * 2] = p1; ws_probs[t * 2 + 1] = p2;

  atomicAdd(&cnt[i1], 1);
  atomicAdd(&cnt[i2], 1);
  __syncthreads();
  atomicAdd(&counts[tid], cnt[tid]);
}

__global__ __launch_bounds__(256) void capacity_kernel(
    const int* __restrict__ counts, const int* __restrict__ ws_idx,
    const float* __restrict__ ws_probs, float* __restrict__ out) {
  const int e = blockIdx.x;
  const int cnt = counts[e];
  if (threadIdx.x == 0) out[(size_t)N_TOK * 4 + e] = (float)cnt;
  if (cnt <= CAP) return;  // cold path: counts ~ mu=512 sigma=22.5, CAP=640 is +5.7 sigma
  for (int i = threadIdx.x; i < N_TOK * 2; i += 256) {
    if (ws_idx[i] != e) continue;
    const float p = ws_probs[i];
    const int tok = i >> 1;
    int rank = 0;
    for (int j = 0; j < N_TOK * 2; ++j) {
      if (ws_idx[j] != e) continue;
      const float q = ws_probs[j];
      if (q > p || (q == p && (j >> 1) < tok)) ++rank;
    }
    if (rank >= CAP) {
      out[i] = 0.0f;                                   // dropped prob
      out[(size_t)N_TOK * 2 + i] = 2147483648.0f;      // INT32_MAX as f32
    }
  }
}

extern "C" void kernel_launch(void* const* d_in, const int* in_sizes, int n_in,
                              void* d_out, int out_size, void* d_ws, size_t ws_size,
                              hipStream_t stream) {
  const float* x = (const float*)d_in[0];
  const float* W = (const float*)d_in[1];
  float* out = (float*)d_out;

  char* ws = (char*)d_ws;
  int*   counts   = (int*)ws;
  int*   ws_idx   = (int*)(ws + 256);
  float* ws_probs = (float*)(ws + 256 + (size_t)N_TOK * 2 * 4);
  float* partials = (float*)(ws + 262400);

  const size_t base = 262400;
  const size_t per  = (size_t)N_TOK * NE * 4;  // 4 MB per K-split partial
  int ks = (ws_size >= base + 8 * per) ? 8 : 4;  // round 2 confirmed ws fits ks=8

  hipMemsetAsync(counts, 0, NE * sizeof(int), stream);
  if (ks == 8) {
    gemm_logits_kernel<8><<<NTILES * 8, 256, 0, stream>>>(x, W, partials);
    route_kernel<8><<<N_TOK / 64, 64, 0, stream>>>(partials, out, ws_idx, ws_probs, counts);
  } else {
    gemm_logits_kernel<4><<<NTILES * 4, 256, 0, stream>>>(x, W, partials);
    route_kernel<4><<<N_TOK / 64, 64, 0, stream>>>(partials, out, ws_idx, ws_probs, counts);
  }
  capacity_kernel<<<NE, 256, 0, stream>>>(counts, ws_idx, ws_probs, out);
}

// Round 4
// 446.474 us; speedup vs baseline: 1.8365x; 1.8365x over previous
//
#include <hip/hip_runtime.h>
#include <math.h>

#define N_TOK  16384
#define DIM    4096
#define NE     64
#define CAP    640
#define KC     32
#define TILE_T 256
#define NTILES (N_TOK / TILE_T)   // 64

// LDS slot: row-major, row padded to 36 floats (144B, 16B-aligned), quad slot
// XOR-swizzled by row>>3 so the inner-loop reads (8 rows, stride 8) and the
// staging writes both spread across banks. q in [0,8) covers KC=32 k.
#define SW(row, q) (((row) * 36) + ((((q) ^ ((row) >> 3)) & 7) << 2))

// ws layout:
// [0,256):               counts (64 int, zeroed per call)
// [256, 256+128K):       ws_idx   (int,   N*2)
// [256+128K, 256+256K):  ws_probs (float, N*2)
// [262400, ...):         partials (KS * 64 * N floats, layout [split][expert][token])

// GEMM: both operands via LDS (the only feed path that sustained rate: R1=174us).
// Per-lane tile 8 tok x 8 exp -> LDS/FMA pipe ratio 6(f+g)/fg = 1.5 (R1 was 2.25).
// Block: 256 thr = 4 waves, 256 tok x 64 exp. Wave: 64 tok x 64 exp;
// lane_t = lane&7 -> tokens lane_t*8..+8, lane_e = lane>>3 -> experts lane_e*8..+8.
template<int KS>
__global__ __launch_bounds__(256, 2) void gemm_logits_kernel(
    const float* __restrict__ x, const float* __restrict__ W,
    float* __restrict__ partials) {
  const int tile   = blockIdx.x % NTILES;
  const int split  = blockIdx.x / NTILES;
  const int klen   = DIM / KS;
  const int k0     = split * klen;
  const int t_base = tile * TILE_T;

  __shared__ float xs[TILE_T * 36];   // 36 KB
  __shared__ float wl[NE * 36];       // 9 KB

  const int tid    = threadIdx.x;
  const int lane   = tid & 63;
  const int wv     = tid >> 6;
  const int lane_t = lane & 7;
  const int lane_e = lane >> 3;
  const int trow   = wv * 64 + lane_t * 8;  // block-relative first token of this lane

  // staging maps
  const int sx_t = tid >> 3;  // 0..31 token row (8 passes of 32)
  const int sx_q = tid & 7;   // k-quad
  const int sw_e = tid >> 2;  // 0..63 expert row
  const int sw_i = tid & 3;   // 2 quads each

  float acc[8][8];
#pragma unroll
  for (int j = 0; j < 8; ++j)
#pragma unroll
    for (int m = 0; m < 8; ++m) acc[j][m] = 0.f;

  for (int kc = 0; kc < klen; kc += KC) {
    const int kg = k0 + kc;
    // stage x tile: 256 tok x 32 k, straight b128 copies, coalesced 128B rows
#pragma unroll
    for (int i = 0; i < 8; ++i) {
      const int t = sx_t + 32 * i;
      const float4 v = *(const float4*)(x + (size_t)(t_base + t) * DIM + kg + sx_q * 4);
      *(float4*)&xs[SW(t, sx_q)] = v;
    }
    // stage w tile: 64 exp x 32 k
#pragma unroll
    for (int i = 0; i < 2; ++i) {
      const int q = sw_i * 2 + i;
      const float4 v = *(const float4*)(W + (size_t)sw_e * DIM + kg + q * 4);
      *(float4*)&wl[SW(sw_e, q)] = v;
    }
    __syncthreads();

#pragma unroll
    for (int q = 0; q < 8; ++q) {  // 8 k-quads
      float4 xf[8], wf[8];
#pragma unroll
      for (int j = 0; j < 8; ++j) xf[j] = *(const float4*)&xs[SW(trow + j, q)];
#pragma unroll
      for (int m = 0; m < 8; ++m) wf[m] = *(const float4*)&wl[SW(lane_e * 8 + m, q)];
#pragma unroll
      for (int j = 0; j < 8; ++j)
#pragma unroll
        for (int m = 0; m < 8; ++m) {
          acc[j][m] = fmaf(xf[j].x, wf[m].x, acc[j][m]);
          acc[j][m] = fmaf(xf[j].y, wf[m].y, acc[j][m]);
          acc[j][m] = fmaf(xf[j].z, wf[m].z, acc[j][m]);
          acc[j][m] = fmaf(xf[j].w, wf[m].w, acc[j][m]);
        }
    }
    __syncthreads();
  }

  // partials[split][expert][token]; per expert row, lane writes its 8
  // consecutive tokens as 2 float4 (full 32B runs -> clean line writes)
  float* outp = partials + (size_t)split * NE * N_TOK + t_base + trow;
#pragma unroll
  for (int m = 0; m < 8; ++m) {
    float* p = outp + (size_t)(lane_e * 8 + m) * N_TOK;
    *(float4*)p       = make_float4(acc[0][m], acc[1][m], acc[2][m], acc[3][m]);
    *(float4*)(p + 4) = make_float4(acc[4][m], acc[5][m], acc[6][m], acc[7][m]);
  }
}

template<int KS>
__global__ __launch_bounds__(64) void route_kernel(
    const float* __restrict__ partials,
    float* __restrict__ out, int* __restrict__ ws_idx,
    float* __restrict__ ws_probs, int* __restrict__ counts) {
  __shared__ int cnt[NE];
  const int tid = threadIdx.x;
  cnt[tid] = 0;
  __syncthreads();
  const int t = blockIdx.x * 64 + tid;

  // top-2 with jax.lax.top_k tie semantics (strict > keeps lower index)
  float b1 = -INFINITY, b2 = -INFINITY;
  int i1 = 0, i2 = 0;
#pragma unroll
  for (int e = 0; e < NE; ++e) {
    float s = partials[(size_t)e * N_TOK + t];  // coalesced across lanes
#pragma unroll
    for (int sp = 1; sp < KS; ++sp)
      s += partials[(size_t)sp * NE * N_TOK + (size_t)e * N_TOK + t];
    if (s > b1)      { b2 = b1; i2 = i1; b1 = s; i1 = e; }
    else if (s > b2) { b2 = s; i2 = e; }
  }
  const float ed = expf(b2 - b1);
  const float p1 = 1.0f / (1.0f + ed);
  const float p2 = ed / (1.0f + ed);

  out[(size_t)t * 2]     = p1;
  out[(size_t)t * 2 + 1] = p2;
  out[(size_t)N_TOK * 2 + t * 2]     = (float)i1;  // indices stored as f32
  out[(size_t)N_TOK * 2 + t * 2 + 1] = (float)i2;
  ws_idx[t * 2] = i1;  ws_idx[t * 2 + 1] = i2;
  ws_probs[t * 2] = p1; ws_probs[t * 2 + 1] = p2;

  atomicAdd(&cnt[i1], 1);
  atomicAdd(&cnt[i2], 1);
  __syncthreads();
  atomicAdd(&counts[tid], cnt[tid]);
}

__global__ __launch_bounds__(256) void capacity_kernel(
    const int* __restrict__ counts, const int* __restrict__ ws_idx,
    const float* __restrict__ ws_probs, float* __restrict__ out) {
  const int e = blockIdx.x;
  const int cnt = counts[e];
  if (threadIdx.x == 0) out[(size_t)N_TOK * 4 + e] = (float)cnt;
  if (cnt <= CAP) return;  // cold path: counts ~ mu=512 sigma=22.5, CAP=640 is +5.7 sigma
  for (int i = threadIdx.x; i < N_TOK * 2; i += 256) {
    if (ws_idx[i] != e) continue;
    const float p = ws_probs[i];
    const int tok = i >> 1;
    int rank = 0;
    for (int j = 0; j < N_TOK * 2; ++j) {
      if (ws_idx[j] != e) continue;
      const float q = ws_probs[j];
      if (q > p || (q == p && (j >> 1) < tok)) ++rank;
    }
    if (rank >= CAP) {
      out[i] = 0.0f;                                   // dropped prob
      out[(size_t)N_TOK * 2 + i] = 2147483648.0f;      // INT32_MAX as f32
    }
  }
}

extern "C" void kernel_launch(void* const* d_in, const int* in_sizes, int n_in,
                              void* d_out, int out_size, void* d_ws, size_t ws_size,
                              hipStream_t stream) {
  const float* x = (const float*)d_in[0];
  const float* W = (const float*)d_in[1];
  float* out = (float*)d_out;

  char* ws = (char*)d_ws;
  int*   counts   = (int*)ws;
  int*   ws_idx   = (int*)(ws + 256);
  float* ws_probs = (float*)(ws + 256 + (size_t)N_TOK * 2 * 4);
  float* partials = (float*)(ws + 262400);

  const size_t base = 262400;
  const size_t per  = (size_t)N_TOK * NE * 4;  // 4 MB per K-split partial
  const int ks = (ws_size >= base + 8 * per) ? 8 : 4;  // rounds 2-3 confirmed ks=8 fits

  hipMemsetAsync(counts, 0, NE * sizeof(int), stream);
  if (ks == 8) {
    gemm_logits_kernel<8><<<NTILES * 8, 256, 0, stream>>>(x, W, partials);
    route_kernel<8><<<N_TOK / 64, 64, 0, stream>>>(partials, out, ws_idx, ws_probs, counts);
  } else {
    gemm_logits_kernel<4><<<NTILES * 4, 256, 0, stream>>>(x, W, partials);
    route_kernel<4><<<N_TOK / 64, 64, 0, stream>>>(partials, out, ws_idx, ws_probs, counts);
  }
  capacity_kernel<<<NE, 256, 0, stream>>>(counts, ws_idx, ws_probs, out);
}